// Round 2
// baseline (1289.557 us; speedup 1.0000x reference)
//
#include <hip/hip_runtime.h>
#include <math.h>

// PLDA pairwise scorer, eigendecomposition-free reformulation.
// out = 2 v_i^T B v_j - q_i - q_j - log_div,  B = (63/64) f(S_w^-1 S_b) S_w^-1,
// f(x) = (63/64) relu(x - 1/63) applied spectrally via Chebyshev poly (deg 28),
// S_w^-1 via Newton-Schulz. ||psi||^2 = tr(f(C)^2).

#define D 128
#define NCLS 256
#define NPC 64
#define MTEST 8192
#define COUNT (NCLS*NPC)
#define DEG 28

// ws layout (float offsets)
#define fMC    0          // 32768 class means [256][128]
#define fMEAN  32768      // 128
#define fSCAL  33000      // [0]=log_div [1]=inv_s [2]=c0 [3]=inv_h; coef at +8 (29); red at +48 (4)
#define fMAT   65536      // 10 matrices of 16384 floats
#define fBBF   262144     // B_bf16: 16384 ushorts
#define fPART  524288     // 64*16384 floats (K3 partials); later reused by U/V
#define fU     524288     // U_bf16: 8192*128 ushorts = 524288 float slots
#define fV     1048576    // V_bf16: same
#define fQ     1572864    // 8192 floats

using short8 = __attribute__((ext_vector_type(8))) short;
using f32x4  = __attribute__((ext_vector_type(4))) float;

__device__ inline unsigned short f2bf(float f) {
  unsigned u = __float_as_uint(f);
  unsigned r = u + 0x7FFFu + ((u >> 16) & 1u);
  return (unsigned short)(r >> 16);
}
__device__ inline float bf2f(unsigned short h) {
  return __uint_as_float(((unsigned)h) << 16);
}

__device__ inline float block_sum(float v, float* red, int tid) {
  #pragma unroll
  for (int off = 32; off > 0; off >>= 1) v += __shfl_down(v, off);
  __syncthreads();
  if ((tid & 63) == 0) red[tid >> 6] = v;
  __syncthreads();
  return red[0] + red[1] + red[2] + red[3];
}

// ---------------- K1: per-class means ----------------
__global__ void k_class_mean(const float* __restrict__ X, float* __restrict__ ws) {
  int k = blockIdx.x, d = threadIdx.x;
  const float* p = X + k * NPC * D + d;
  float s = 0.f;
  #pragma unroll
  for (int n = 0; n < NPC; n++) s += p[n * D];
  ws[fMC + k * D + d] = s * (1.0f / NPC);
}

// ---------------- K2: global mean ----------------
__global__ void k_global_mean(float* __restrict__ ws) {
  int d = threadIdx.x;
  float s = 0.f;
  for (int k = 0; k < NCLS; k++) s += ws[fMC + k * D + d];
  ws[fMEAN + d] = s * (1.0f / NCLS);
}

// ---------------- K3: Gt partials = X^T X over 256-row chunks (bf16 MFMA) ----------------
__global__ __launch_bounds__(256) void k_gt_partial(const float* __restrict__ X, float* __restrict__ ws) {
  __shared__ unsigned short xt[128 * 256]; // 64 KB, xt[d][s] transposed, swizzled
  int b = blockIdx.x, tid = threadIdx.x;
  const float* Xc = X + b * 256 * D;
  for (int idx = tid; idx < 256 * D; idx += 256) {
    int s = idx >> 7, d = idx & 127;
    unsigned byte = ((unsigned)(d * 512 + s * 2)) ^ (((unsigned)(d & 7)) << 4);
    *(unsigned short*)((char*)xt + byte) = f2bf(Xc[idx]);
  }
  __syncthreads();
  int w = tid >> 6, lane = tid & 63;
  int wr = (w >> 1) * 64, wc = (w & 1) * 64;
  f32x4 acc[4][4] = {};
  for (int ks = 0; ks < 8; ks++) {
    int kb = ks * 32 + (lane >> 4) * 8;
    short8 af[4];
    #pragma unroll
    for (int mt = 0; mt < 4; mt++) {
      int r = wr + mt * 16 + (lane & 15);
      unsigned byte = ((unsigned)(r * 512 + kb * 2)) ^ (((unsigned)(r & 7)) << 4);
      af[mt] = *(short8*)((char*)xt + byte);
    }
    #pragma unroll
    for (int nt = 0; nt < 4; nt++) {
      int c = wc + nt * 16 + (lane & 15);
      unsigned byte = ((unsigned)(c * 512 + kb * 2)) ^ (((unsigned)(c & 7)) << 4);
      short8 bfr = *(short8*)((char*)xt + byte);
      #pragma unroll
      for (int mt = 0; mt < 4; mt++)
        acc[mt][nt] = __builtin_amdgcn_mfma_f32_16x16x32_bf16(af[mt], bfr, acc[mt][nt], 0, 0, 0);
    }
  }
  float* outp = ws + fPART + b * 16384;
  #pragma unroll
  for (int mt = 0; mt < 4; mt++)
    #pragma unroll
    for (int nt = 0; nt < 4; nt++)
      #pragma unroll
      for (int r = 0; r < 4; r++) {
        int row = wr + mt * 16 + (lane >> 4) * 4 + r;
        int col = wc + nt * 16 + (lane & 15);
        outp[row * 128 + col] = acc[mt][nt][r];
      }
}

// ---------------- split-bf16 128x128x128 matmul: Cg = scale*(Ag·Bg) ----------------
// A read directly from global (rows), B staged transposed hi/lo in LDS.
// REQUIREMENT: Cg must not alias Ag or Bg.
__device__ void wg_mm(const float* Ag, const float* Bg, float* Cg, float scale,
                      unsigned short* Bhi, unsigned short* Blo, int tid) {
  __syncthreads();
  for (int idx = tid; idx < 16384; idx += 256) {
    int k = idx >> 7, c = idx & 127;
    float v = Bg[idx];
    unsigned short h = f2bf(v);
    unsigned short l = f2bf(v - bf2f(h));
    unsigned byte = ((unsigned)(c * 256 + k * 2)) ^ (((unsigned)(c & 7)) << 4);
    *(unsigned short*)((char*)Bhi + byte) = h;
    *(unsigned short*)((char*)Blo + byte) = l;
  }
  __syncthreads();
  int w = tid >> 6, lane = tid & 63;
  int wr = (w >> 1) * 64, wc = (w & 1) * 64;
  f32x4 acc[4][4] = {};
  for (int ks = 0; ks < 4; ks++) {
    int kb = ks * 32 + (lane >> 4) * 8;
    short8 ah[4], al[4];
    #pragma unroll
    for (int mt = 0; mt < 4; mt++) {
      int r = wr + mt * 16 + (lane & 15);
      const float* ap = Ag + r * 128 + kb;
      short8 hi, lo;
      #pragma unroll
      for (int i = 0; i < 8; i++) {
        float a = ap[i];
        unsigned short hb = f2bf(a);
        hi[i] = (short)hb;
        lo[i] = (short)f2bf(a - bf2f(hb));
      }
      ah[mt] = hi; al[mt] = lo;
    }
    #pragma unroll
    for (int nt = 0; nt < 4; nt++) {
      int c = wc + nt * 16 + (lane & 15);
      unsigned byte = ((unsigned)(c * 256 + kb * 2)) ^ (((unsigned)(c & 7)) << 4);
      short8 bh = *(short8*)((char*)Bhi + byte);
      short8 bl = *(short8*)((char*)Blo + byte);
      #pragma unroll
      for (int mt = 0; mt < 4; mt++) {
        f32x4 a0 = acc[mt][nt];
        a0 = __builtin_amdgcn_mfma_f32_16x16x32_bf16(ah[mt], bh, a0, 0, 0, 0);
        a0 = __builtin_amdgcn_mfma_f32_16x16x32_bf16(al[mt], bh, a0, 0, 0, 0);
        a0 = __builtin_amdgcn_mfma_f32_16x16x32_bf16(ah[mt], bl, a0, 0, 0, 0);
        acc[mt][nt] = a0;
      }
    }
  }
  #pragma unroll
  for (int mt = 0; mt < 4; mt++)
    #pragma unroll
    for (int nt = 0; nt < 4; nt++)
      #pragma unroll
      for (int r = 0; r < 4; r++) {
        int row = wr + mt * 16 + (lane >> 4) * 4 + r;
        int col = wc + nt * 16 + (lane & 15);
        Cg[row * 128 + col] = acc[mt][nt][r] * scale;
      }
  __syncthreads();
}

// ---------------- K4: the whole fit, single block ----------------
__global__ __launch_bounds__(256) void k_fit(float* __restrict__ ws) {
  __shared__ unsigned short sStage[32768]; // 64 KB
  int tid = threadIdx.x;
  float* SW = ws + fMAT;
  float* SB = SW + 16384;
  float* Zb = SB + 16384;
  float* Tb = Zb + 16384;
  float* Z2 = Tb + 16384;
  float* XH = Z2 + 16384;
  float* BA = XH + 16384;
  float* BB = BA + 16384;
  float* PP = BB + 16384;
  float* BM = PP + 16384;
  float* scal = ws + fSCAL;
  float* coef = ws + fSCAL + 8;
  float* red  = ws + fSCAL + 48;
  unsigned short* Bhi = sStage;
  unsigned short* Blo = sStage + 16384;

  // Phase 1: S_b = Mc^T Mc / 256 - m m^T (MFMA over K=256)
  {
    const float* Mc = ws + fMC;
    for (int idx = tid; idx < NCLS * D; idx += 256) {
      int kk = idx >> 7, dd = idx & 127;
      unsigned byte = ((unsigned)(dd * 512 + kk * 2)) ^ (((unsigned)(dd & 7)) << 4);
      *(unsigned short*)((char*)sStage + byte) = f2bf(Mc[idx]);
    }
    __syncthreads();
    int w = tid >> 6, lane = tid & 63;
    int wr = (w >> 1) * 64, wc = (w & 1) * 64;
    f32x4 acc[4][4] = {};
    for (int ks = 0; ks < 8; ks++) {
      int kb = ks * 32 + (lane >> 4) * 8;
      short8 af[4];
      #pragma unroll
      for (int mt = 0; mt < 4; mt++) {
        int r = wr + mt * 16 + (lane & 15);
        unsigned byte = ((unsigned)(r * 512 + kb * 2)) ^ (((unsigned)(r & 7)) << 4);
        af[mt] = *(short8*)((char*)sStage + byte);
      }
      #pragma unroll
      for (int nt = 0; nt < 4; nt++) {
        int c = wc + nt * 16 + (lane & 15);
        unsigned byte = ((unsigned)(c * 512 + kb * 2)) ^ (((unsigned)(c & 7)) << 4);
        short8 bfr = *(short8*)((char*)sStage + byte);
        #pragma unroll
        for (int mt = 0; mt < 4; mt++)
          acc[mt][nt] = __builtin_amdgcn_mfma_f32_16x16x32_bf16(af[mt], bfr, acc[mt][nt], 0, 0, 0);
      }
    }
    const float* mv = ws + fMEAN;
    #pragma unroll
    for (int mt = 0; mt < 4; mt++)
      #pragma unroll
      for (int nt = 0; nt < 4; nt++)
        #pragma unroll
        for (int r = 0; r < 4; r++) {
          int row = wr + mt * 16 + (lane >> 4) * 4 + r;
          int col = wc + nt * 16 + (lane & 15);
          SB[row * 128 + col] = acc[mt][nt][r] * (1.0f / 256.0f) - mv[row] * mv[col];
        }
    __syncthreads();
  }

  // Phase 2: reduce Gt partials -> S_w = Gt/count - SB - m m^T
  {
    const float* mv = ws + fMEAN;
    const float* part = ws + fPART;
    for (int idx = tid; idx < 16384; idx += 256) {
      float s = 0.f;
      for (int p = 0; p < 64; p++) s += part[p * 16384 + idx];
      int r = idx >> 7, c = idx & 127;
      SW[idx] = s * (1.0f / COUNT) - SB[idx] - mv[r] * mv[c];
    }
    __syncthreads();
  }

  // Phase 3: inv_s = 128/tr(S_w)
  {
    float v = 0.f;
    if (tid < 128) v = SW[tid * 129];
    float t = block_sum(v, red, tid);
    if (tid == 0) scal[1] = 128.0f / t;
    __syncthreads();
  }

  // Phase 4: Sn = S_w * inv_s (in place)
  {
    float is = scal[1];
    for (int idx = tid; idx < 16384; idx += 256) SW[idx] *= is;
    __syncthreads();
  }

  // Phase 5: Newton-Schulz: Z -> Sn^-1
  float* Zp = Zb; float* Zn = Z2;
  {
    for (int idx = tid; idx < 16384; idx += 256)
      Zp[idx] = ((idx >> 7) == (idx & 127)) ? 1.0f : 0.0f;
    for (int it = 0; it < 5; it++) {
      wg_mm(SW, Zp, Tb, 1.0f, Bhi, Blo, tid);
      for (int idx = tid; idx < 16384; idx += 256) {
        float dg = ((idx >> 7) == (idx & 127)) ? 2.0f : 0.0f;
        Tb[idx] = dg - Tb[idx];
      }
      wg_mm(Zp, Tb, Zn, 1.0f, Bhi, Blo, tid);
      float* tmp = Zp; Zp = Zn; Zn = tmp;
    }
  }

  // Phase 6: T = Z * S_b  (= s*C); tr(C^2); Chebyshev coefficients
  wg_mm(Zp, SB, Tb, 1.0f, Bhi, Blo, tid);
  {
    float local = 0.f;
    for (int idx = tid; idx < 16384; idx += 256) {
      int r = idx >> 7, c = idx & 127;
      local += Tb[idx] * Tb[c * 128 + r];
    }
    float t = block_sum(local, red, tid);
    if (tid == 0) {
      float is = scal[1];
      float trC2 = t * is * is;
      float Lam = 1.02f * sqrtf(fmaxf(trC2, 1e-30f));
      float lo = -0.02f * Lam, hi = Lam;
      float c0 = 0.5f * (hi + lo), hh = 0.5f * (hi - lo);
      float t0 = 1.0f / 63.0f;
      float x0 = (t0 - c0) / hh;
      x0 = fminf(fmaxf(x0, -1.0f), 1.0f);
      float th = acosf(x0);
      float SCc = 0.984375f * hh; // (63/64)*h
      const float PI = 3.14159265358979f;
      coef[0] = SCc * (2.0f / PI) * (sinf(th) - x0 * th);
      coef[1] = SCc * (2.0f / PI) * (0.5f * th + 0.25f * sinf(2.0f * th) - x0 * sinf(th));
      for (int j = 2; j <= DEG; j++) {
        float fj = (float)j;
        coef[j] = SCc * (2.0f / PI) *
          (0.5f * (sinf((fj + 1.0f) * th) / (fj + 1.0f) + sinf((fj - 1.0f) * th) / (fj - 1.0f))
           - x0 * sinf(fj * th) / fj);
      }
      scal[2] = c0; scal[3] = 1.0f / hh;
    }
    __syncthreads();
  }

  // Phase 7: XH = (T*inv_s - c0 I) * inv_h
  {
    float is = scal[1], c0 = scal[2], ih = scal[3];
    for (int idx = tid; idx < 16384; idx += 256) {
      float dg = ((idx >> 7) == (idx & 127)) ? c0 : 0.0f;
      XH[idx] = (Tb[idx] * is - dg) * ih;
    }
    __syncthreads();
  }

  // Phase 8: Clenshaw for F = f(C)
  float* pb1; float* pb2;
  {
    float aN = coef[DEG], aN1 = coef[DEG - 1];
    for (int idx = tid; idx < 16384; idx += 256) {
      float dg = ((idx >> 7) == (idx & 127)) ? 1.0f : 0.0f;
      BA[idx] = aN * dg;
      BB[idx] = aN1 * dg + 2.0f * aN * XH[idx];
    }
    pb1 = BB; pb2 = BA;
    for (int k = DEG - 2; k >= 1; k--) {
      wg_mm(XH, pb1, PP, 1.0f, Bhi, Blo, tid);
      float ak = coef[k];
      for (int idx = tid; idx < 16384; idx += 256) {
        float dg = ((idx >> 7) == (idx & 127)) ? 1.0f : 0.0f;
        pb2[idx] = ak * dg + 2.0f * PP[idx] - pb2[idx];
      }
      float* tmp = pb1; pb1 = pb2; pb2 = tmp;
    }
    wg_mm(XH, pb1, PP, 1.0f, Bhi, Blo, tid);
    float a0 = coef[0];
    for (int idx = tid; idx < 16384; idx += 256) {
      float dg = ((idx >> 7) == (idx & 127)) ? 1.0f : 0.0f;
      pb2[idx] = 0.5f * a0 * dg + PP[idx] - pb2[idx];
    }
    __syncthreads();
    // F = pb2
  }

  // Phase 9: ||psi||^2 = tr(F^2) -> log_div
  {
    float local = 0.f;
    for (int idx = tid; idx < 16384; idx += 256) {
      int r = idx >> 7, c = idx & 127;
      local += pb2[idx] * pb2[c * 128 + r];
    }
    float t = block_sum(local, red, tid);
    if (tid == 0) {
      float trF2 = fmaxf(t, 1e-30f);
      scal[0] = 0.5f * (128.0f * 1.8378770664093453f + 0.5f * logf(trF2));
    }
    __syncthreads();
  }

  // Phase 10: B = (63/64) * F * Z * inv_s
  wg_mm(pb2, Zp, BM, 0.984375f * scal[1], Bhi, Blo, tid);

  // Phase 11: symmetrize + bf16
  {
    unsigned short* Bbf = (unsigned short*)(ws + fBBF);
    for (int idx = tid; idx < 16384; idx += 256) {
      int r = idx >> 7, c = idx & 127;
      Bbf[idx] = f2bf(0.5f * (BM[idx] + BM[c * 128 + r]));
    }
  }
}

// ---------------- K5: V = test - mean (bf16); U = V*B (bf16) ----------------
__global__ __launch_bounds__(256) void k_latent(const float* __restrict__ test, float* __restrict__ ws) {
  __shared__ unsigned short vh[16384]; // 32 KB swizzled
  int blk = blockIdx.x, tid = threadIdx.x;
  const float* tb = test + blk * 128 * D;
  unsigned short* Vbf = (unsigned short*)(ws + fV);
  for (int idx = tid; idx < 16384; idx += 256) {
    int r = idx >> 7, c = idx & 127;
    float v = tb[idx] - ws[fMEAN + c];
    unsigned short h = f2bf(v);
    unsigned byte = ((unsigned)(r * 256 + c * 2)) ^ (((unsigned)(r & 7)) << 4);
    *(unsigned short*)((char*)vh + byte) = h;
    Vbf[blk * 16384 + idx] = h;
  }
  __syncthreads();
  int w = tid >> 6, lane = tid & 63;
  int wr = (w >> 1) * 64, wc = (w & 1) * 64;
  const unsigned short* Bbf = (const unsigned short*)(ws + fBBF);
  f32x4 acc[4][4] = {};
  for (int ks = 0; ks < 4; ks++) {
    int kb = ks * 32 + (lane >> 4) * 8;
    short8 af[4], bfv[4];
    #pragma unroll
    for (int mt = 0; mt < 4; mt++) {
      int r = wr + mt * 16 + (lane & 15);
      unsigned byte = ((unsigned)(r * 256 + kb * 2)) ^ (((unsigned)(r & 7)) << 4);
      af[mt] = *(short8*)((char*)vh + byte);
    }
    #pragma unroll
    for (int nt = 0; nt < 4; nt++) {
      int c = wc + nt * 16 + (lane & 15);
      bfv[nt] = *(const short8*)(Bbf + c * 128 + kb); // B symmetric: B[k][c]=B[c][k]
    }
    #pragma unroll
    for (int mt = 0; mt < 4; mt++)
      #pragma unroll
      for (int nt = 0; nt < 4; nt++)
        acc[mt][nt] = __builtin_amdgcn_mfma_f32_16x16x32_bf16(af[mt], bfv[nt], acc[mt][nt], 0, 0, 0);
  }
  unsigned short* Ubf = (unsigned short*)(ws + fU);
  #pragma unroll
  for (int mt = 0; mt < 4; mt++)
    #pragma unroll
    for (int nt = 0; nt < 4; nt++)
      #pragma unroll
      for (int r = 0; r < 4; r++) {
        int row = wr + mt * 16 + (lane >> 4) * 4 + r;
        int col = wc + nt * 16 + (lane & 15);
        Ubf[(blk * 128 + row) * 128 + col] = f2bf(acc[mt][nt][r]);
      }
}

// ---------------- K5b: q_i = U_i . V_i ----------------
__global__ void k_q(float* __restrict__ ws) {
  int i = blockIdx.x * 256 + threadIdx.x;
  const short8* U = (const short8*)((const unsigned short*)(ws + fU) + i * 128);
  const short8* V = (const short8*)((const unsigned short*)(ws + fV) + i * 128);
  float s = 0.f;
  for (int t = 0; t < 16; t++) {
    short8 u = U[t], v = V[t];
    #pragma unroll
    for (int j = 0; j < 8; j++)
      s += bf2f((unsigned short)u[j]) * bf2f((unsigned short)v[j]);
  }
  ws[fQ + i] = s;
}

// ---------------- K6: out = 2 U V^T - q_i - q_j - log_div ----------------
__global__ __launch_bounds__(256) void k_pair(const float* __restrict__ ws, float* __restrict__ out) {
  __shared__ float qi[128];
  __shared__ float qj[128];
  __shared__ float sld;
  int bi = blockIdx.x, bj = blockIdx.y, tid = threadIdx.x;
  if (tid < 128) qi[tid] = ws[fQ + bi * 128 + tid];
  else qj[tid - 128] = ws[fQ + bj * 128 + (tid - 128)];
  if (tid == 0) sld = ws[fSCAL + 0];
  __syncthreads();
  int w = tid >> 6, lane = tid & 63;
  int wr = (w >> 1) * 64, wc = (w & 1) * 64;
  const unsigned short* Ubf = (const unsigned short*)(ws + fU);
  const unsigned short* Vbf = (const unsigned short*)(ws + fV);
  f32x4 acc[4][4] = {};
  for (int ks = 0; ks < 4; ks++) {
    int kb = ks * 32 + (lane >> 4) * 8;
    short8 af[4], bfv[4];
    #pragma unroll
    for (int mt = 0; mt < 4; mt++) {
      int r = bi * 128 + wr + mt * 16 + (lane & 15);
      af[mt] = *(const short8*)(Ubf + r * 128 + kb);
    }
    #pragma unroll
    for (int nt = 0; nt < 4; nt++) {
      int c = bj * 128 + wc + nt * 16 + (lane & 15);
      bfv[nt] = *(const short8*)(Vbf + c * 128 + kb);
    }
    #pragma unroll
    for (int mt = 0; mt < 4; mt++)
      #pragma unroll
      for (int nt = 0; nt < 4; nt++)
        acc[mt][nt] = __builtin_amdgcn_mfma_f32_16x16x32_bf16(af[mt], bfv[nt], acc[mt][nt], 0, 0, 0);
  }
  float ld = sld;
  #pragma unroll
  for (int mt = 0; mt < 4; mt++)
    #pragma unroll
    for (int nt = 0; nt < 4; nt++)
      #pragma unroll
      for (int r = 0; r < 4; r++) {
        int row = wr + mt * 16 + (lane >> 4) * 4 + r;
        int col = wc + nt * 16 + (lane & 15);
        float g = acc[mt][nt][r];
        out[(size_t)(bi * 128 + row) * MTEST + (bj * 128 + col)] =
          2.0f * g - qi[row] - qj[col] - ld;
      }
}

extern "C" void kernel_launch(void* const* d_in, const int* in_sizes, int n_in,
                              void* d_out, int out_size, void* d_ws, size_t ws_size,
                              hipStream_t stream) {
  (void)in_sizes; (void)n_in; (void)out_size; (void)ws_size;
  const float* X = (const float*)d_in[0];    // src_seq [256,64,128]
  const float* test = (const float*)d_in[1]; // [8192,128]
  float* out = (float*)d_out;
  float* ws = (float*)d_ws;

  k_class_mean<<<NCLS, 128, 0, stream>>>(X, ws);
  k_global_mean<<<1, 128, 0, stream>>>(ws);
  k_gt_partial<<<64, 256, 0, stream>>>(X, ws);
  k_fit<<<1, 256, 0, stream>>>(ws);
  k_latent<<<64, 256, 0, stream>>>(test, ws);
  k_q<<<32, 256, 0, stream>>>(ws);
  k_pair<<<dim3(64, 64), 256, 0, stream>>>(ws, out);
}

// Round 3
// 776.721 us; speedup vs baseline: 1.6603x; 1.6603x over previous
//
#include <hip/hip_runtime.h>
#include <math.h>

// PLDA pairwise scorer, eigendecomposition-free.
// out = 2 v_i^T B v_j - q_i - q_j - log_div,  B = (63/64) f(S_w^-1 S_b) S_w^-1,
// f(x) = (63/64) relu(x - 1/63) spectrally via Chebyshev (deg 20) on
// [-0.02L, L], L = 1.03*(tr C^8)^(1/8) (rigorous >= lambda_max).
// S_w^-1 via 3 Newton-Schulz iters. All intermediates dual-plane bf16 (hi+lo).

#define D 128
#define NCLS 256
#define NPC 64
#define MTEST 8192
#define COUNT (NCLS*NPC)
#define DEG 20
#define NSIT 3

// ws float-offset layout
#define fMC    0          // McT bf16 [128][256] ushort = 16384 float slots
#define fMEAN  32768      // 128 f32
#define fSCAL  33000      // [0]=log_div [2]=c0 [3]=1/h [4]=th [5]=x0 [6]=SCc; coef at +8 (21); red at +48 (16)
#define fMAT   65536      // 10 dual-plane matrices x 16384 float slots
#define fSWRAW 229376     // 16384 f32 (Gram sum)
#define fBBF   262144     // B single-plane bf16 16384 ushort
#define fPART  524288     // 64*16384 f32 partials (dead after k_reduce; reused by U/V)
#define fU     524288
#define fV     1048576
#define fQ     1572864

using short8 = __attribute__((ext_vector_type(8))) short;
using f32x4  = __attribute__((ext_vector_type(4))) float;

__device__ inline unsigned short f2bf(float f) {
  unsigned u = __float_as_uint(f);
  unsigned r = u + 0x7FFFu + ((u >> 16) & 1u);
  return (unsigned short)(r >> 16);
}
__device__ inline float bf2f(unsigned short h) {
  return __uint_as_float(((unsigned)h) << 16);
}
__device__ inline unsigned short* matU(float* ws, int m) {
  return (unsigned short*)(ws + fMAT) + m * 32768;
}
__device__ inline float valU(const unsigned short* m, int idx) {
  return bf2f(m[idx]) + bf2f(m[idx + 16384]);
}
__device__ inline void load8(const unsigned short* m, int idx, float* v) {
  short8 h = *(const short8*)(m + idx);
  short8 l = *(const short8*)(m + 16384 + idx);
  #pragma unroll
  for (int j = 0; j < 8; j++) v[j] = bf2f((unsigned short)h[j]) + bf2f((unsigned short)l[j]);
}
__device__ inline void store8(unsigned short* m, int idx, const float* v) {
  short8 h, l;
  #pragma unroll
  for (int j = 0; j < 8; j++) {
    unsigned short hb = f2bf(v[j]);
    h[j] = (short)hb;
    l[j] = (short)f2bf(v[j] - bf2f(hb));
  }
  *(short8*)(m + idx) = h;
  *(short8*)(m + 16384 + idx) = l;
}

// 1024-thread block sum (16 waves)
__device__ inline float block_sum(float v, float* red, int tid) {
  #pragma unroll
  for (int off = 32; off > 0; off >>= 1) v += __shfl_down(v, off);
  __syncthreads();
  if ((tid & 63) == 0) red[tid >> 6] = v;
  __syncthreads();
  float s = 0.f;
  #pragma unroll
  for (int i = 0; i < 16; i++) s += red[i];
  return s;
}

// ---------------- K1: per-class means -> McT bf16 [d][k] ----------------
__global__ void k_class_mean(const float* __restrict__ X, float* __restrict__ ws) {
  int k = blockIdx.x, d = threadIdx.x;
  const float* p = X + k * NPC * D + d;
  float s = 0.f;
  #pragma unroll
  for (int n = 0; n < NPC; n++) s += p[n * D];
  ((unsigned short*)ws)[d * 256 + k] = f2bf(s * (1.0f / NPC));
}

// ---------------- K2: global mean (from McT) ----------------
__global__ void k_global_mean(float* __restrict__ ws) {
  int d = threadIdx.x;
  const unsigned short* McT = (const unsigned short*)ws;
  float s = 0.f;
  for (int k = 0; k < NCLS; k++) s += bf2f(McT[d * 256 + k]);
  ws[fMEAN + d] = s * (1.0f / NCLS);
}

// ---------------- K3: Gram partials = X^T X over 256-row chunks ----------------
__global__ __launch_bounds__(256) void k_gt_partial(const float* __restrict__ X, float* __restrict__ ws) {
  __shared__ unsigned short xt[128 * 256]; // 64 KB, [d][s] swizzled
  int b = blockIdx.x, tid = threadIdx.x;
  const float* Xc = X + b * 256 * D;
  for (int idx = tid; idx < 256 * D; idx += 256) {
    int s = idx >> 7, d = idx & 127;
    unsigned byte = ((unsigned)(d * 512 + s * 2)) ^ (((unsigned)(d & 7)) << 4);
    *(unsigned short*)((char*)xt + byte) = f2bf(Xc[idx]);
  }
  __syncthreads();
  int w = tid >> 6, lane = tid & 63;
  int wr = (w >> 1) * 64, wc = (w & 1) * 64;
  f32x4 acc[4][4] = {};
  for (int ks = 0; ks < 8; ks++) {
    int kb = ks * 32 + (lane >> 4) * 8;
    short8 af[4];
    #pragma unroll
    for (int mt = 0; mt < 4; mt++) {
      int r = wr + mt * 16 + (lane & 15);
      unsigned byte = ((unsigned)(r * 512 + kb * 2)) ^ (((unsigned)(r & 7)) << 4);
      af[mt] = *(short8*)((char*)xt + byte);
    }
    #pragma unroll
    for (int nt = 0; nt < 4; nt++) {
      int c = wc + nt * 16 + (lane & 15);
      unsigned byte = ((unsigned)(c * 512 + kb * 2)) ^ (((unsigned)(c & 7)) << 4);
      short8 bfr = *(short8*)((char*)xt + byte);
      #pragma unroll
      for (int mt = 0; mt < 4; mt++)
        acc[mt][nt] = __builtin_amdgcn_mfma_f32_16x16x32_bf16(af[mt], bfr, acc[mt][nt], 0, 0, 0);
    }
  }
  float* outp = ws + fPART + b * 16384;
  #pragma unroll
  for (int mt = 0; mt < 4; mt++)
    #pragma unroll
    for (int nt = 0; nt < 4; nt++)
      #pragma unroll
      for (int r = 0; r < 4; r++) {
        int row = wr + mt * 16 + (lane >> 4) * 4 + r;
        int col = wc + nt * 16 + (lane & 15);
        outp[row * 128 + col] = acc[mt][nt][r];
      }
}

// ---------------- K3b: reduce 64 Gram partials ----------------
__global__ void k_reduce(float* __restrict__ ws) {
  int idx = blockIdx.x * 256 + threadIdx.x;
  const float* part = ws + fPART;
  float s = 0.f;
  #pragma unroll 8
  for (int p = 0; p < 64; p++) s += part[p * 16384 + idx];
  ws[fSWRAW + idx] = s;
}

// ---------------- dual-plane split-bf16 128^3 matmul (16 waves) ----------------
// A read from global planes; B staged transposed hi/lo to swizzled LDS.
// C must not alias A or B. A==B allowed.
__device__ void wg_mm(const unsigned short* __restrict__ A, const unsigned short* __restrict__ B,
                      unsigned short* __restrict__ Cm, float scale,
                      unsigned short* Bhi, unsigned short* Blo, int tid) {
  __syncthreads();
  // stage B: thread run = (c, k0): 8 along-k ushorts -> one ds_write_b128 per plane
  #pragma unroll
  for (int run = 0; run < 2; run++) {
    int t = tid + run * 1024;
    int c = t & 127, k0 = (t >> 7) * 8;
    short8 h, l;
    #pragma unroll
    for (int j = 0; j < 8; j++) {
      h[j] = (short)B[(k0 + j) * 128 + c];
      l[j] = (short)B[16384 + (k0 + j) * 128 + c];
    }
    unsigned byte = ((unsigned)(c * 256 + k0 * 2)) ^ (((unsigned)(c & 7)) << 4);
    *(short8*)((char*)Bhi + byte) = h;
    *(short8*)((char*)Blo + byte) = l;
  }
  __syncthreads();
  int w = tid >> 6, lane = tid & 63;
  int wr = (w >> 2) * 32, wc = (w & 3) * 32;
  f32x4 acc[2][2] = {};
  for (int ks = 0; ks < 4; ks++) {
    int kb = ks * 32 + (lane >> 4) * 8;
    short8 ah[2], al[2];
    #pragma unroll
    for (int mt = 0; mt < 2; mt++) {
      int r = wr + mt * 16 + (lane & 15);
      ah[mt] = *(const short8*)(A + r * 128 + kb);
      al[mt] = *(const short8*)(A + 16384 + r * 128 + kb);
    }
    #pragma unroll
    for (int nt = 0; nt < 2; nt++) {
      int c = wc + nt * 16 + (lane & 15);
      unsigned byte = ((unsigned)(c * 256 + kb * 2)) ^ (((unsigned)(c & 7)) << 4);
      short8 bh = *(short8*)((char*)Bhi + byte);
      short8 bl = *(short8*)((char*)Blo + byte);
      #pragma unroll
      for (int mt = 0; mt < 2; mt++) {
        f32x4 a0 = acc[mt][nt];
        a0 = __builtin_amdgcn_mfma_f32_16x16x32_bf16(ah[mt], bh, a0, 0, 0, 0);
        a0 = __builtin_amdgcn_mfma_f32_16x16x32_bf16(al[mt], bh, a0, 0, 0, 0);
        a0 = __builtin_amdgcn_mfma_f32_16x16x32_bf16(ah[mt], bl, a0, 0, 0, 0);
        acc[mt][nt] = a0;
      }
    }
  }
  #pragma unroll
  for (int mt = 0; mt < 2; mt++)
    #pragma unroll
    for (int nt = 0; nt < 2; nt++)
      #pragma unroll
      for (int r = 0; r < 4; r++) {
        int row = wr + mt * 16 + (lane >> 4) * 4 + r;
        int col = wc + nt * 16 + (lane & 15);
        float g = acc[mt][nt][r] * scale;
        unsigned short hb = f2bf(g);
        Cm[row * 128 + col] = hb;
        Cm[16384 + row * 128 + col] = f2bf(g - bf2f(hb));
      }
  __syncthreads();
}

// ---------------- K4: fit, single block, 1024 threads ----------------
__global__ __launch_bounds__(1024) void k_fit(float* __restrict__ ws) {
  __shared__ unsigned short sLds[32768]; // 64 KB
  unsigned short* Bhi = sLds;
  unsigned short* Blo = sLds + 16384;
  int tid = threadIdx.x;
  float* scal = ws + fSCAL;
  float* coef = ws + fSCAL + 8;
  float* red  = ws + fSCAL + 48;
  const float* mv = ws + fMEAN;
  unsigned short* SW = matU(ws, 0);
  unsigned short* SB = matU(ws, 1);
  unsigned short* Zb = matU(ws, 2);
  unsigned short* Tm = matU(ws, 3);
  unsigned short* Z2 = matU(ws, 4);
  unsigned short* XH = matU(ws, 5);
  unsigned short* BA = matU(ws, 6);
  unsigned short* BB = matU(ws, 7);
  unsigned short* PP = matU(ws, 8);
  unsigned short* BM = matU(ws, 9);

  // Phase 1: SB = McT McT^T / 256 - m m^T  (K=256, single-bf16, direct global)
  {
    const unsigned short* Mc = (const unsigned short*)ws;
    int w = tid >> 6, lane = tid & 63;
    int wr = (w >> 2) * 32, wc = (w & 3) * 32;
    f32x4 acc[2][2] = {};
    for (int ks = 0; ks < 8; ks++) {
      int kb = ks * 32 + (lane >> 4) * 8;
      short8 af[2], bfv[2];
      #pragma unroll
      for (int mt = 0; mt < 2; mt++) {
        int r = wr + mt * 16 + (lane & 15);
        af[mt] = *(const short8*)(Mc + r * 256 + kb);
      }
      #pragma unroll
      for (int nt = 0; nt < 2; nt++) {
        int c = wc + nt * 16 + (lane & 15);
        bfv[nt] = *(const short8*)(Mc + c * 256 + kb);
      }
      #pragma unroll
      for (int mt = 0; mt < 2; mt++)
        #pragma unroll
        for (int nt = 0; nt < 2; nt++)
          acc[mt][nt] = __builtin_amdgcn_mfma_f32_16x16x32_bf16(af[mt], bfv[nt], acc[mt][nt], 0, 0, 0);
    }
    #pragma unroll
    for (int mt = 0; mt < 2; mt++)
      #pragma unroll
      for (int nt = 0; nt < 2; nt++)
        #pragma unroll
        for (int r = 0; r < 4; r++) {
          int row = wr + mt * 16 + (lane >> 4) * 4 + r;
          int col = wc + nt * 16 + (lane & 15);
          float g = acc[mt][nt][r] * (1.0f / 256.0f) - mv[row] * mv[col];
          unsigned short hb = f2bf(g);
          SB[row * 128 + col] = hb;
          SB[16384 + row * 128 + col] = f2bf(g - bf2f(hb));
        }
    __syncthreads();
  }

  // Phase 2a: tr(S_w) -> inv_s
  float inv_s;
  {
    float dv = 0.f;
    if (tid < 128)
      dv = ws[fSWRAW + tid * 129] * (1.0f / COUNT) - valU(SB, tid * 129) - mv[tid] * mv[tid];
    float tr = block_sum(dv, red, tid);
    inv_s = 128.0f / tr;
  }

  // Phase 2: SW = (Gram/count - SB - m m^T) * inv_s  (dual-plane)
  for (int i8 = tid * 8; i8 < 16384; i8 += 8192) {
    int row = i8 >> 7, c0 = i8 & 127;
    float sb[8], v[8];
    load8(SB, i8, sb);
    float mr = mv[row];
    #pragma unroll
    for (int j = 0; j < 8; j++)
      v[j] = (ws[fSWRAW + i8 + j] * (1.0f / COUNT) - sb[j] - mr * mv[c0 + j]) * inv_s;
    store8(SW, i8, v);
  }

  // Z = I
  for (int i8 = tid * 8; i8 < 16384; i8 += 8192) {
    int row = i8 >> 7, c0 = i8 & 127;
    float v[8];
    #pragma unroll
    for (int j = 0; j < 8; j++) v[j] = (c0 + j == row) ? 1.0f : 0.0f;
    store8(Zb, i8, v);
  }

  // Phase 5: Newton-Schulz (3 iters)
  unsigned short* Zp = Zb; unsigned short* Zn = Z2;
  for (int it = 0; it < NSIT; it++) {
    wg_mm(SW, Zp, Tm, 1.0f, Bhi, Blo, tid);
    for (int i8 = tid * 8; i8 < 16384; i8 += 8192) {
      int row = i8 >> 7, c0 = i8 & 127;
      float v[8];
      load8(Tm, i8, v);
      #pragma unroll
      for (int j = 0; j < 8; j++) v[j] = ((c0 + j == row) ? 2.0f : 0.0f) - v[j];
      store8(Tm, i8, v);
    }
    wg_mm(Zp, Tm, Zn, 1.0f, Bhi, Blo, tid);
    unsigned short* t = Zp; Zp = Zn; Zn = t;
  }

  // Phase 6: T = Z*SB (= C/inv_s); C2 = T^2; C4 = T^4; Lam = inv_s*(tr T^8)^{1/8}
  wg_mm(Zp, SB, Tm, 1.0f, Bhi, Blo, tid);
  wg_mm(Tm, Tm, BA, 1.0f, Bhi, Blo, tid);   // C2 in BA (dead before Clenshaw init)
  wg_mm(BA, BA, BB, 1.0f, Bhi, Blo, tid);   // C4 in BB
  {
    float local = 0.f;
    for (int idx = tid; idx < 16384; idx += 1024) {
      int r = idx >> 7, c = idx & 127;
      local += valU(BB, idx) * valU(BB, c * 128 + r);
    }
    float t8 = block_sum(local, red, tid);
    if (tid == 0) {
      float Lam = inv_s * sqrtf(sqrtf(sqrtf(fmaxf(t8, 1e-37f))));
      Lam *= 1.03f;
      float lo = -0.02f * Lam, hi = Lam;
      float c0 = 0.5f * (hi + lo), hh = 0.5f * (hi - lo);
      float x0 = (1.0f / 63.0f - c0) / hh;
      x0 = fminf(fmaxf(x0, -1.0f), 1.0f);
      float th = acosf(x0);
      scal[2] = c0; scal[3] = 1.0f / hh;
      scal[4] = th; scal[5] = x0; scal[6] = 0.984375f * hh;
    }
    __syncthreads();
    if (tid <= DEG) {
      float th = scal[4], x0 = scal[5], SCc = scal[6];
      const float PI = 3.14159265358979f;
      float v;
      if (tid == 0) v = SCc * (2.0f / PI) * (sinf(th) - x0 * th);
      else if (tid == 1) v = SCc * (2.0f / PI) * (0.5f * th + 0.25f * sinf(2.0f * th) - x0 * sinf(th));
      else {
        float fj = (float)tid;
        v = SCc * (2.0f / PI) *
            (0.5f * (sinf((fj + 1.0f) * th) / (fj + 1.0f) + sinf((fj - 1.0f) * th) / (fj - 1.0f))
             - x0 * sinf(fj * th) / fj);
      }
      coef[tid] = v;
    }
    __syncthreads();
  }

  // Phase 7: XH = (T*inv_s - c0 I) / h
  {
    float c0 = scal[2], ih = scal[3];
    for (int i8 = tid * 8; i8 < 16384; i8 += 8192) {
      int row = i8 >> 7, cc = i8 & 127;
      float v[8];
      load8(Tm, i8, v);
      #pragma unroll
      for (int j = 0; j < 8; j++)
        v[j] = (v[j] * inv_s - ((cc + j == row) ? c0 : 0.0f)) * ih;
      store8(XH, i8, v);
    }
    __syncthreads();
  }

  // Phase 8: Clenshaw F = f(C)
  unsigned short* pb1; unsigned short* pb2;
  {
    float aN = coef[DEG], aN1 = coef[DEG - 1];
    for (int i8 = tid * 8; i8 < 16384; i8 += 8192) {
      int row = i8 >> 7, cc = i8 & 127;
      float xh[8], va[8], vb[8];
      load8(XH, i8, xh);
      #pragma unroll
      for (int j = 0; j < 8; j++) {
        float dg = (cc + j == row) ? 1.0f : 0.0f;
        va[j] = aN * dg;
        vb[j] = aN1 * dg + 2.0f * aN * xh[j];
      }
      store8(BA, i8, va);
      store8(BB, i8, vb);
    }
    pb1 = BB; pb2 = BA;
    for (int k = DEG - 2; k >= 1; k--) {
      wg_mm(XH, pb1, PP, 1.0f, Bhi, Blo, tid);
      float ak = coef[k];
      for (int i8 = tid * 8; i8 < 16384; i8 += 8192) {
        int row = i8 >> 7, cc = i8 & 127;
        float pp[8], p2[8];
        load8(PP, i8, pp);
        load8(pb2, i8, p2);
        #pragma unroll
        for (int j = 0; j < 8; j++)
          p2[j] = ak * ((cc + j == row) ? 1.0f : 0.0f) + 2.0f * pp[j] - p2[j];
        store8(pb2, i8, p2);
      }
      unsigned short* t = pb1; pb1 = pb2; pb2 = t;
    }
    wg_mm(XH, pb1, PP, 1.0f, Bhi, Blo, tid);
    float a0 = coef[0];
    for (int i8 = tid * 8; i8 < 16384; i8 += 8192) {
      int row = i8 >> 7, cc = i8 & 127;
      float pp[8], p2[8];
      load8(PP, i8, pp);
      load8(pb2, i8, p2);
      #pragma unroll
      for (int j = 0; j < 8; j++)
        p2[j] = 0.5f * a0 * ((cc + j == row) ? 1.0f : 0.0f) + pp[j] - p2[j];
      store8(pb2, i8, p2);
    }
    __syncthreads();
  }

  // Phase 9: tr(F^2) -> log_div
  {
    float local = 0.f;
    for (int idx = tid; idx < 16384; idx += 1024) {
      int r = idx >> 7, c = idx & 127;
      local += valU(pb2, idx) * valU(pb2, c * 128 + r);
    }
    float t = block_sum(local, red, tid);
    if (tid == 0) {
      float trF2 = fmaxf(t, 1e-30f);
      scal[0] = 0.5f * (128.0f * 1.8378770664093453f + 0.5f * logf(trF2));
    }
  }

  // Phase 10: B = (63/64) * F * Z * inv_s
  wg_mm(pb2, Zp, BM, 0.984375f * inv_s, Bhi, Blo, tid);

  // Phase 11: symmetrize -> single-plane bf16
  {
    unsigned short* Bbf = (unsigned short*)(ws + fBBF);
    for (int idx = tid; idx < 16384; idx += 1024) {
      int r = idx >> 7, c = idx & 127;
      Bbf[idx] = f2bf(0.5f * (valU(BM, idx) + valU(BM, c * 128 + r)));
    }
  }
}

// ---------------- K5: V = test - mean (bf16); U = V*B ----------------
__global__ __launch_bounds__(256) void k_latent(const float* __restrict__ test, float* __restrict__ ws) {
  __shared__ unsigned short vh[16384];
  int blk = blockIdx.x, tid = threadIdx.x;
  const float* tb = test + blk * 128 * D;
  unsigned short* Vbf = (unsigned short*)(ws + fV);
  for (int idx = tid; idx < 16384; idx += 256) {
    int r = idx >> 7, c = idx & 127;
    float v = tb[idx] - ws[fMEAN + c];
    unsigned short h = f2bf(v);
    unsigned byte = ((unsigned)(r * 256 + c * 2)) ^ (((unsigned)(r & 7)) << 4);
    *(unsigned short*)((char*)vh + byte) = h;
    Vbf[blk * 16384 + idx] = h;
  }
  __syncthreads();
  int w = tid >> 6, lane = tid & 63;
  int wr = (w >> 1) * 64, wc = (w & 1) * 64;
  const unsigned short* Bbf = (const unsigned short*)(ws + fBBF);
  f32x4 acc[4][4] = {};
  for (int ks = 0; ks < 4; ks++) {
    int kb = ks * 32 + (lane >> 4) * 8;
    short8 af[4], bfv[4];
    #pragma unroll
    for (int mt = 0; mt < 4; mt++) {
      int r = wr + mt * 16 + (lane & 15);
      unsigned byte = ((unsigned)(r * 256 + kb * 2)) ^ (((unsigned)(r & 7)) << 4);
      af[mt] = *(short8*)((char*)vh + byte);
    }
    #pragma unroll
    for (int nt = 0; nt < 4; nt++) {
      int c = wc + nt * 16 + (lane & 15);
      bfv[nt] = *(const short8*)(Bbf + c * 128 + kb); // B symmetric
    }
    #pragma unroll
    for (int mt = 0; mt < 4; mt++)
      #pragma unroll
      for (int nt = 0; nt < 4; nt++)
        acc[mt][nt] = __builtin_amdgcn_mfma_f32_16x16x32_bf16(af[mt], bfv[nt], acc[mt][nt], 0, 0, 0);
  }
  unsigned short* Ubf = (unsigned short*)(ws + fU);
  #pragma unroll
  for (int mt = 0; mt < 4; mt++)
    #pragma unroll
    for (int nt = 0; nt < 4; nt++)
      #pragma unroll
      for (int r = 0; r < 4; r++) {
        int row = wr + mt * 16 + (lane >> 4) * 4 + r;
        int col = wc + nt * 16 + (lane & 15);
        Ubf[(blk * 128 + row) * 128 + col] = f2bf(acc[mt][nt][r]);
      }
}

// ---------------- K5b: q_i = U_i . V_i ----------------
__global__ void k_q(float* __restrict__ ws) {
  int i = blockIdx.x * 256 + threadIdx.x;
  const short8* U = (const short8*)((const unsigned short*)(ws + fU) + i * 128);
  const short8* V = (const short8*)((const unsigned short*)(ws + fV) + i * 128);
  float s = 0.f;
  for (int t = 0; t < 16; t++) {
    short8 u = U[t], v = V[t];
    #pragma unroll
    for (int j = 0; j < 8; j++)
      s += bf2f((unsigned short)u[j]) * bf2f((unsigned short)v[j]);
  }
  ws[fQ + i] = s;
}

// ---------------- K6: out = 2 U V^T - q_i - q_j - log_div ----------------
__global__ __launch_bounds__(256) void k_pair(const float* __restrict__ ws, float* __restrict__ out) {
  __shared__ float qi[128];
  __shared__ float qj[128];
  __shared__ float sld;
  int bi = blockIdx.x, bj = blockIdx.y, tid = threadIdx.x;
  if (tid < 128) qi[tid] = ws[fQ + bi * 128 + tid];
  else qj[tid - 128] = ws[fQ + bj * 128 + (tid - 128)];
  if (tid == 0) sld = ws[fSCAL + 0];
  __syncthreads();
  int w = tid >> 6, lane = tid & 63;
  int wr = (w >> 1) * 64, wc = (w & 1) * 64;
  const unsigned short* Ubf = (const unsigned short*)(ws + fU);
  const unsigned short* Vbf = (const unsigned short*)(ws + fV);
  f32x4 acc[4][4] = {};
  for (int ks = 0; ks < 4; ks++) {
    int kb = ks * 32 + (lane >> 4) * 8;
    short8 af[4], bfv[4];
    #pragma unroll
    for (int mt = 0; mt < 4; mt++) {
      int r = bi * 128 + wr + mt * 16 + (lane & 15);
      af[mt] = *(const short8*)(Ubf + r * 128 + kb);
    }
    #pragma unroll
    for (int nt = 0; nt < 4; nt++) {
      int c = bj * 128 + wc + nt * 16 + (lane & 15);
      bfv[nt] = *(const short8*)(Vbf + c * 128 + kb);
    }
    #pragma unroll
    for (int mt = 0; mt < 4; mt++)
      #pragma unroll
      for (int nt = 0; nt < 4; nt++)
        acc[mt][nt] = __builtin_amdgcn_mfma_f32_16x16x32_bf16(af[mt], bfv[nt], acc[mt][nt], 0, 0, 0);
  }
  float ld = sld;
  #pragma unroll
  for (int mt = 0; mt < 4; mt++)
    #pragma unroll
    for (int nt = 0; nt < 4; nt++)
      #pragma unroll
      for (int r = 0; r < 4; r++) {
        int row = wr + mt * 16 + (lane >> 4) * 4 + r;
        int col = wc + nt * 16 + (lane & 15);
        float g = acc[mt][nt][r];
        out[(size_t)(bi * 128 + row) * MTEST + (bj * 128 + col)] =
          2.0f * g - qi[row] - qj[col] - ld;
      }
}

extern "C" void kernel_launch(void* const* d_in, const int* in_sizes, int n_in,
                              void* d_out, int out_size, void* d_ws, size_t ws_size,
                              hipStream_t stream) {
  (void)in_sizes; (void)n_in; (void)out_size; (void)ws_size;
  const float* X = (const float*)d_in[0];
  const float* test = (const float*)d_in[1];
  float* out = (float*)d_out;
  float* ws = (float*)d_ws;

  k_class_mean<<<NCLS, 128, 0, stream>>>(X, ws);
  k_global_mean<<<1, 128, 0, stream>>>(ws);
  k_gt_partial<<<64, 256, 0, stream>>>(X, ws);
  k_reduce<<<64, 256, 0, stream>>>(ws);
  k_fit<<<1, 1024, 0, stream>>>(ws);
  k_latent<<<64, 256, 0, stream>>>(test, ws);
  k_q<<<32, 256, 0, stream>>>(ws);
  k_pair<<<dim3(64, 64), 256, 0, stream>>>(ws, out);
}

// Round 5
// 308.479 us; speedup vs baseline: 4.1804x; 2.5179x over previous
//
#include <hip/hip_runtime.h>
#include <math.h>

// PLDA pairwise scorer, eigendecomposition-free, all-symmetric formulation.
// Y ~= S_wn^{-1/2} (NS sqrt), M = Y*SB*Y (symmetric), F = f0(inv_s*M) via
// degree-24 bivariate Chebyshev (T_k(T5(X))*T_r(X), k,r<=4),
// B = (63/64)*inv_s*Y*F*Y.  out = 2 v_i^T B v_j - q_i - q_j - log_div.
// Every matmul B-operand is symmetric -> read rows as columns, no LDS
// staging, tiny 4-block kernels chained by stream order.

#define D 128
#define NCLS 256
#define NPC 64
#define MTEST 8192
#define COUNT (NCLS*NPC)

// ws float-offset layout (disjoint! U/V are 524288 fl each)
#define fMC    0                      // McT bf16 [128][256] = 16384 fl slots
#define fMEAN  16384                  // 128 f32
#define fSCAL  16640                  // scalars/coefs/partials (256 f32)
#define fMAT   32768                  // 24 dual-plane matrices x 16384 fl
#define fSWRAW (fMAT + 21*16384)      // slot 21: 16384 f32 Gram sum
#define fPART  425984                 // 64*16384 f32 partials (dead after k_reduce)
#define fU     425984                 // 524288 fl -> ends 950272
#define fV     950272                 // 524288 fl -> ends 1474560
#define fQ     1474560                // 8192 fl  -> ends 1482752
#define fBBF   1482752                // 8192 fl  -> ends 1490944 (~5.96 MB)

using short8 = __attribute__((ext_vector_type(8))) short;
using f32x4  = __attribute__((ext_vector_type(4))) float;

__device__ inline unsigned short f2bf(float f) {
  unsigned u = __float_as_uint(f);
  unsigned r = u + 0x7FFFu + ((u >> 16) & 1u);
  return (unsigned short)(r >> 16);
}
__device__ inline float bf2f(unsigned short h) {
  return __uint_as_float(((unsigned)h) << 16);
}
__device__ inline float valU(const unsigned short* m, int idx) {
  return bf2f(m[idx]) + bf2f(m[idx + 16384]);
}
__device__ inline void storeDual(unsigned short* m, int idx, float g) {
  unsigned short hb = f2bf(g);
  m[idx] = hb;
  m[16384 + idx] = f2bf(g - bf2f(hb));
}
__device__ inline unsigned short* matSlot(float* ws, int m) {
  return (unsigned short*)(ws + fMAT) + (size_t)m * 32768;
}

// ---------------- K1: per-class means -> McT bf16 [d][k] ----------------
__global__ void k_class_mean(const float* __restrict__ X, float* __restrict__ ws) {
  int k = blockIdx.x, d = threadIdx.x;
  const float* p = X + k * NPC * D + d;
  float s = 0.f;
  #pragma unroll
  for (int n = 0; n < NPC; n++) s += p[n * D];
  ((unsigned short*)ws)[d * 256 + k] = f2bf(s * (1.0f / NPC));
}

// ---------------- K2: global mean ----------------
__global__ void k_global_mean(float* __restrict__ ws) {
  int d = threadIdx.x;
  const unsigned short* McT = (const unsigned short*)ws;
  float s = 0.f;
  for (int k = 0; k < NCLS; k++) s += bf2f(McT[d * 256 + k]);
  ws[fMEAN + d] = s * (1.0f / NCLS);
}

// ---------------- K3: Gram partials = X^T X over 256-row chunks ----------------
__global__ __launch_bounds__(256) void k_gt_partial(const float* __restrict__ X, float* __restrict__ ws) {
  __shared__ unsigned short xt[128 * 256]; // 64 KB, [d][s] swizzled
  int b = blockIdx.x, tid = threadIdx.x;
  const float* Xc = X + b * 256 * D;
  for (int idx = tid; idx < 256 * D; idx += 256) {
    int s = idx >> 7, d = idx & 127;
    unsigned byte = ((unsigned)(d * 512 + s * 2)) ^ (((unsigned)(d & 7)) << 4);
    *(unsigned short*)((char*)xt + byte) = f2bf(Xc[idx]);
  }
  __syncthreads();
  int w = tid >> 6, lane = tid & 63;
  int wr = (w >> 1) * 64, wc = (w & 1) * 64;
  f32x4 acc[4][4] = {};
  for (int ks = 0; ks < 8; ks++) {
    int kb = ks * 32 + (lane >> 4) * 8;
    short8 af[4];
    #pragma unroll
    for (int mt = 0; mt < 4; mt++) {
      int r = wr + mt * 16 + (lane & 15);
      unsigned byte = ((unsigned)(r * 512 + kb * 2)) ^ (((unsigned)(r & 7)) << 4);
      af[mt] = *(short8*)((char*)xt + byte);
    }
    #pragma unroll
    for (int nt = 0; nt < 4; nt++) {
      int c = wc + nt * 16 + (lane & 15);
      unsigned byte = ((unsigned)(c * 512 + kb * 2)) ^ (((unsigned)(c & 7)) << 4);
      short8 bfr = *(short8*)((char*)xt + byte);
      #pragma unroll
      for (int mt = 0; mt < 4; mt++)
        acc[mt][nt] = __builtin_amdgcn_mfma_f32_16x16x32_bf16(af[mt], bfr, acc[mt][nt], 0, 0, 0);
    }
  }
  float* outp = ws + fPART + b * 16384;
  #pragma unroll
  for (int mt = 0; mt < 4; mt++)
    #pragma unroll
    for (int nt = 0; nt < 4; nt++)
      #pragma unroll
      for (int r = 0; r < 4; r++) {
        int row = wr + mt * 16 + (lane >> 4) * 4 + r;
        int col = wc + nt * 16 + (lane & 15);
        outp[row * 128 + col] = acc[mt][nt][r];
      }
}

// ---------------- K3b: reduce 64 Gram partials -> SWRAW f32 ----------------
__global__ void k_reduce(float* __restrict__ ws) {
  int idx = blockIdx.x * 256 + threadIdx.x;
  const float* part = ws + fPART;
  float s = 0.f;
  #pragma unroll 8
  for (int p = 0; p < 64; p++) s += part[p * 16384 + idx];
  ws[fSWRAW + idx] = s;
}

// ---------------- K4: SB = McT McT^T/256 - m m^T; + S_w trace partials ----------------
__global__ __launch_bounds__(256) void k_sb(float* __restrict__ ws) {
  __shared__ float red[4];
  const unsigned short* Mc = (const unsigned short*)ws;
  const float* mv = ws + fMEAN;
  const float* swraw = ws + fSWRAW;
  unsigned short* SB = matSlot(ws, 1);
  float* scal = ws + fSCAL;
  int tid = threadIdx.x, b = blockIdx.x;
  int w = tid >> 6, lane = tid & 63;
  int brow = b * 32, wcol = w * 32;
  f32x4 acc[2][2] = {};
  for (int ks = 0; ks < 8; ks++) {
    int kb = ks * 32 + (lane >> 4) * 8;
    short8 af[2], bfv[2];
    #pragma unroll
    for (int mt = 0; mt < 2; mt++) {
      int r = brow + mt * 16 + (lane & 15);
      af[mt] = *(const short8*)(Mc + r * 256 + kb);
    }
    #pragma unroll
    for (int nt = 0; nt < 2; nt++) {
      int c = wcol + nt * 16 + (lane & 15);
      bfv[nt] = *(const short8*)(Mc + c * 256 + kb);
    }
    #pragma unroll
    for (int mt = 0; mt < 2; mt++)
      #pragma unroll
      for (int nt = 0; nt < 2; nt++)
        acc[mt][nt] = __builtin_amdgcn_mfma_f32_16x16x32_bf16(af[mt], bfv[nt], acc[mt][nt], 0, 0, 0);
  }
  float tsum = 0.f;
  #pragma unroll
  for (int mt = 0; mt < 2; mt++)
    #pragma unroll
    for (int nt = 0; nt < 2; nt++)
      #pragma unroll
      for (int r = 0; r < 4; r++) {
        int row = brow + mt * 16 + (lane >> 4) * 4 + r;
        int col = wcol + nt * 16 + (lane & 15);
        int idx = row * 128 + col;
        float g = acc[mt][nt][r] * (1.0f / 256.0f) - mv[row] * mv[col];
        storeDual(SB, idx, g);
        if (row == col)
          tsum += swraw[row * 129] * (1.0f / COUNT) - g - mv[row] * mv[row];
      }
  #pragma unroll
  for (int off = 32; off > 0; off >>= 1) tsum += __shfl_down(tsum, off);
  if (lane == 0) red[w] = tsum;
  __syncthreads();
  if (tid == 0) scal[64 + b] = red[0] + red[1] + red[2] + red[3];
}

// ---------------- K5: SW = normalized S_w; Y1 = 1.5I - 0.5 SW ----------------
__global__ __launch_bounds__(256) void k_swfin(float* __restrict__ ws) {
  float* scal = ws + fSCAL;
  float inv_s = 128.0f / (scal[64] + scal[65] + scal[66] + scal[67]);
  const float* mv = ws + fMEAN;
  const float* swraw = ws + fSWRAW;
  const unsigned short* SB = matSlot(ws, 1);
  unsigned short* SW = matSlot(ws, 0);
  unsigned short* Y1 = matSlot(ws, 2);
  int gid = blockIdx.x * 256 + threadIdx.x;
  #pragma unroll
  for (int t = 0; t < 4; t++) {
    int idx = gid * 4 + t;
    int row = idx >> 7, col = idx & 127;
    float sb = valU(SB, idx);
    float s = (swraw[idx] * (1.0f / COUNT) - sb - mv[row] * mv[col]) * inv_s;
    storeDual(SW, idx, s);
    float y = ((row == col) ? 1.5f : 0.0f) - 0.5f * s;
    storeDual(Y1, idx, y);
  }
  if (blockIdx.x == 0 && threadIdx.x == 0) scal[1] = inv_s;
}

// ---------------- generic 128^3 dual-bf16 matmul, symmetric B-operand ----------------
// C = alpha_eff*(A*B) + beta*E1 + gamma*E2 + delta*I ; optional ||C||_F^2 partials
__global__ __launch_bounds__(256) void k_mm(
    const unsigned short* __restrict__ A, const unsigned short* __restrict__ B,
    unsigned short* __restrict__ C, const unsigned short* __restrict__ E1,
    const unsigned short* __restrict__ E2, float alpha,
    const float* __restrict__ alpha_ptr, float beta, float gamma, float delta,
    float* __restrict__ scal, int trace_slot) {
  __shared__ float red[4];
  int tid = threadIdx.x, b = blockIdx.x;
  int w = tid >> 6, lane = tid & 63;
  int brow = b * 32, wcol = w * 32;
  f32x4 acc[2][2] = {};
  #pragma unroll
  for (int ks = 0; ks < 4; ks++) {
    int kb = ks * 32 + (lane >> 4) * 8;
    short8 ah[2], al[2], bh[2], bl[2];
    #pragma unroll
    for (int mt = 0; mt < 2; mt++) {
      int r = brow + mt * 16 + (lane & 15);
      ah[mt] = *(const short8*)(A + r * 128 + kb);
      al[mt] = *(const short8*)(A + 16384 + r * 128 + kb);
    }
    #pragma unroll
    for (int nt = 0; nt < 2; nt++) {
      int c = wcol + nt * 16 + (lane & 15);
      bh[nt] = *(const short8*)(B + c * 128 + kb);      // row c == col c (symmetric)
      bl[nt] = *(const short8*)(B + 16384 + c * 128 + kb);
    }
    #pragma unroll
    for (int mt = 0; mt < 2; mt++)
      #pragma unroll
      for (int nt = 0; nt < 2; nt++) {
        f32x4 a0 = acc[mt][nt];
        a0 = __builtin_amdgcn_mfma_f32_16x16x32_bf16(ah[mt], bh[nt], a0, 0, 0, 0);
        a0 = __builtin_amdgcn_mfma_f32_16x16x32_bf16(al[mt], bh[nt], a0, 0, 0, 0);
        a0 = __builtin_amdgcn_mfma_f32_16x16x32_bf16(ah[mt], bl[nt], a0, 0, 0, 0);
        acc[mt][nt] = a0;
      }
  }
  float aeff = alpha * (alpha_ptr ? alpha_ptr[0] : 1.0f);
  float tsum = 0.0f;
  #pragma unroll
  for (int mt = 0; mt < 2; mt++)
    #pragma unroll
    for (int nt = 0; nt < 2; nt++)
      #pragma unroll
      for (int r = 0; r < 4; r++) {
        int row = brow + mt * 16 + (lane >> 4) * 4 + r;
        int col = wcol + nt * 16 + (lane & 15);
        int idx = row * 128 + col;
        float g = acc[mt][nt][r] * aeff;
        if (E1) g += beta * (bf2f(E1[idx]) + bf2f(E1[16384 + idx]));
        if (E2) g += gamma * (bf2f(E2[idx]) + bf2f(E2[16384 + idx]));
        if (row == col) g += delta;
        storeDual(C, idx, g);
        tsum += g * g;
      }
  if (trace_slot >= 0) {
    #pragma unroll
    for (int off = 32; off > 0; off >>= 1) tsum += __shfl_down(tsum, off);
    if (lane == 0) red[w] = tsum;
    __syncthreads();
    if (tid == 0) scal[trace_slot + b] = red[0] + red[1] + red[2] + red[3];
  }
}

// ---------------- K6: interval + Chebyshev coefs + bivariate transform ----------------
__global__ void k_coef(float* __restrict__ ws) {
  if (threadIdx.x != 0) return;
  float* scal = ws + fSCAL;
  float s8 = scal[68] + scal[69] + scal[70] + scal[71];  // ||M^4||_F^2 = tr(M^8)
  float inv_s = scal[1];
  float Lam = 1.03f * sqrtf(sqrtf(sqrtf(fmaxf(s8, 1e-37f))));
  float lo = -0.02f * Lam, hi = Lam;
  float c0 = 0.5f * (hi + lo), h = 0.5f * (hi - lo);
  float ih = 1.0f / h;
  // g(mu) = (63/64)*inv_s*relu(mu - mu*), mu* = (1/63)/inv_s  (lambda = inv_s*mu)
  float t0 = (1.0f / 63.0f) / inv_s;
  float x0 = fminf(fmaxf((t0 - c0) * ih, -1.0f), 1.0f);
  float th = acosf(x0);
  float SCc = 0.984375f * inv_s * h;
  const float PI = 3.14159265358979f;
  float a[25];
  a[0] = SCc * (2.0f / PI) * (sinf(th) - x0 * th);
  a[1] = SCc * (2.0f / PI) * (0.5f * th + 0.25f * sinf(2.0f * th) - x0 * sinf(th));
  for (int j = 2; j <= 24; j++) {
    float fj = (float)j;
    a[j] = SCc * (2.0f / PI) *
        (0.5f * (sinf((fj + 1.0f) * th) / (fj + 1.0f) + sinf((fj - 1.0f) * th) / (fj - 1.0f))
         - x0 * sinf(fj * th) / fj);
  }
  // bivariate transform: p = sum_j at_j T_j(X) -> sum_{k,r} c[k][r] T_k(Y) T_r(X)
  float at[25];
  at[0] = 0.5f * a[0];
  for (int j = 1; j <= 24; j++) at[j] = a[j];
  float c[5][5];
  for (int k = 0; k < 5; k++) for (int r = 0; r < 5; r++) c[k][r] = 0.f;
  for (int j = 24; j >= 5; --j) {
    int k = j / 5, r = j - 5 * k;
    if (r == 0) c[k][0] += at[j];
    else { c[k][r] += 2.0f * at[j]; at[5 * k - r] -= at[j]; }
  }
  for (int r = 0; r < 5; r++) c[0][r] += at[r];
  for (int k = 0; k < 5; k++)
    for (int r = 0; r < 5; r++) scal[32 + k * 5 + r] = c[k][r];
  scal[2] = c0; scal[3] = ih;
  scal[7] = 0.984375f * inv_s;  // B final scale
}

// ---------------- K7: XH = ih*(M - c0 I); T2 = 2 XH^2 - I (from C2) ----------------
__global__ __launch_bounds__(256) void k_xh_t2(float* __restrict__ ws) {
  float* scal = ws + fSCAL;
  float c0 = scal[2], ih = scal[3];
  float a2 = 2.0f * ih * ih, b2 = -4.0f * c0 * ih * ih, g2 = 2.0f * c0 * c0 * ih * ih - 1.0f;
  const unsigned short* M  = matSlot(ws, 8);
  const unsigned short* C2 = matSlot(ws, 9);
  unsigned short* XH = matSlot(ws, 11);
  unsigned short* T2 = matSlot(ws, 12);
  int gid = blockIdx.x * 256 + threadIdx.x;
  #pragma unroll
  for (int t = 0; t < 4; t++) {
    int idx = gid * 4 + t;
    int row = idx >> 7, col = idx & 127;
    float m = valU(M, idx), c2v = valU(C2, idx);
    float dg = (row == col) ? 1.0f : 0.0f;
    storeDual(XH, idx, ih * m - ih * c0 * dg);
    storeDual(T2, idx, a2 * c2v + b2 * m + g2 * dg);
  }
}

// ---------------- K8: G_k = sum_r c[k][r] T_r(X), k=0..4 ----------------
__global__ __launch_bounds__(256) void k_gform(float* __restrict__ ws) {
  float* scal = ws + fSCAL;
  const unsigned short* XH = matSlot(ws, 11);
  const unsigned short* T2 = matSlot(ws, 12);
  const unsigned short* T3 = matSlot(ws, 13);
  const unsigned short* T4 = matSlot(ws, 14);
  int gid = blockIdx.x * 256 + threadIdx.x;
  #pragma unroll
  for (int t = 0; t < 4; t++) {
    int idx = gid * 4 + t;
    int row = idx >> 7, col = idx & 127;
    float dg = (row == col) ? 1.0f : 0.0f;
    float x1 = valU(XH, idx), x2 = valU(T2, idx), x3 = valU(T3, idx), x4 = valU(T4, idx);
    #pragma unroll
    for (int k = 0; k < 5; k++) {
      float g = scal[32 + k * 5 + 0] * dg + scal[32 + k * 5 + 1] * x1 +
                scal[32 + k * 5 + 2] * x2 + scal[32 + k * 5 + 3] * x3 +
                scal[32 + k * 5 + 4] * x4;
      storeDual(matSlot(ws, 16 + k), idx, g);
    }
  }
}

// ---------------- K9: symmetrize Bq -> single bf16; log_div ----------------
__global__ __launch_bounds__(256) void k_sym(float* __restrict__ ws) {
  float* scal = ws + fSCAL;
  const unsigned short* Bq = matSlot(ws, 7);
  unsigned short* Bbf = (unsigned short*)(ws + fBBF);
  int gid = blockIdx.x * 256 + threadIdx.x;
  #pragma unroll
  for (int t = 0; t < 4; t++) {
    int idx = gid * 4 + t;
    int r = idx >> 7, c = idx & 127;
    Bbf[idx] = f2bf(0.5f * (valU(Bq, idx) + valU(Bq, c * 128 + r)));
  }
  if (blockIdx.x == 0 && threadIdx.x == 0) {
    float trF2 = fmaxf(scal[72] + scal[73] + scal[74] + scal[75], 1e-30f);
    scal[0] = 0.5f * (128.0f * 1.8378770664093453f + 0.5f * logf(trF2));
  }
}

// ---------------- K10: V = test - mean (bf16); U = V*B ----------------
__global__ __launch_bounds__(256) void k_latent(const float* __restrict__ test, float* __restrict__ ws) {
  __shared__ unsigned short vh[16384];
  int blk = blockIdx.x, tid = threadIdx.x;
  const float* tb = test + blk * 128 * D;
  unsigned short* Vbf = (unsigned short*)(ws + fV);
  for (int idx = tid; idx < 16384; idx += 256) {
    int r = idx >> 7, c = idx & 127;
    float v = tb[idx] - ws[fMEAN + c];
    unsigned short h = f2bf(v);
    unsigned byte = ((unsigned)(r * 256 + c * 2)) ^ (((unsigned)(r & 7)) << 4);
    *(unsigned short*)((char*)vh + byte) = h;
    Vbf[blk * 16384 + idx] = h;
  }
  __syncthreads();
  int w = tid >> 6, lane = tid & 63;
  int wr = (w >> 1) * 64, wc = (w & 1) * 64;
  const unsigned short* Bbf = (const unsigned short*)(ws + fBBF);
  f32x4 acc[4][4] = {};
  for (int ks = 0; ks < 4; ks++) {
    int kb = ks * 32 + (lane >> 4) * 8;
    short8 af[4], bfv[4];
    #pragma unroll
    for (int mt = 0; mt < 4; mt++) {
      int r = wr + mt * 16 + (lane & 15);
      unsigned byte = ((unsigned)(r * 256 + kb * 2)) ^ (((unsigned)(r & 7)) << 4);
      af[mt] = *(short8*)((char*)vh + byte);
    }
    #pragma unroll
    for (int nt = 0; nt < 4; nt++) {
      int c = wc + nt * 16 + (lane & 15);
      bfv[nt] = *(const short8*)(Bbf + c * 128 + kb); // B symmetric
    }
    #pragma unroll
    for (int mt = 0; mt < 4; mt++)
      #pragma unroll
      for (int nt = 0; nt < 4; nt++)
        acc[mt][nt] = __builtin_amdgcn_mfma_f32_16x16x32_bf16(af[mt], bfv[nt], acc[mt][nt], 0, 0, 0);
  }
  unsigned short* Ubf = (unsigned short*)(ws + fU);
  #pragma unroll
  for (int mt = 0; mt < 4; mt++)
    #pragma unroll
    for (int nt = 0; nt < 4; nt++)
      #pragma unroll
      for (int r = 0; r < 4; r++) {
        int row = wr + mt * 16 + (lane >> 4) * 4 + r;
        int col = wc + nt * 16 + (lane & 15);
        Ubf[(blk * 128 + row) * 128 + col] = f2bf(acc[mt][nt][r]);
      }
}

// ---------------- K11: q_i = U_i . V_i ----------------
__global__ void k_q(float* __restrict__ ws) {
  int i = blockIdx.x * 256 + threadIdx.x;
  const short8* U = (const short8*)((const unsigned short*)(ws + fU) + i * 128);
  const short8* V = (const short8*)((const unsigned short*)(ws + fV) + i * 128);
  float s = 0.f;
  for (int t = 0; t < 16; t++) {
    short8 u = U[t], v = V[t];
    #pragma unroll
    for (int j = 0; j < 8; j++)
      s += bf2f((unsigned short)u[j]) * bf2f((unsigned short)v[j]);
  }
  ws[fQ + i] = s;
}

// ---------------- K12: out = 2 U V^T - q_i - q_j - log_div ----------------
__global__ __launch_bounds__(256) void k_pair(const float* __restrict__ ws, float* __restrict__ out) {
  __shared__ float qi[128];
  __shared__ float qj[128];
  __shared__ float sld;
  int bi = blockIdx.x, bj = blockIdx.y, tid = threadIdx.x;
  if (tid < 128) qi[tid] = ws[fQ + bi * 128 + tid];
  else qj[tid - 128] = ws[fQ + bj * 128 + (tid - 128)];
  if (tid == 0) sld = ws[fSCAL + 0];
  __syncthreads();
  int w = tid >> 6, lane = tid & 63;
  int wr = (w >> 1) * 64, wc = (w & 1) * 64;
  const unsigned short* Ubf = (const unsigned short*)(ws + fU);
  const unsigned short* Vbf = (const unsigned short*)(ws + fV);
  f32x4 acc[4][4] = {};
  for (int ks = 0; ks < 4; ks++) {
    int kb = ks * 32 + (lane >> 4) * 8;
    short8 af[4], bfv[4];
    #pragma unroll
    for (int mt = 0; mt < 4; mt++) {
      int r = bi * 128 + wr + mt * 16 + (lane & 15);
      af[mt] = *(const short8*)(Ubf + r * 128 + kb);
    }
    #pragma unroll
    for (int nt = 0; nt < 4; nt++) {
      int c = bj * 128 + wc + nt * 16 + (lane & 15);
      bfv[nt] = *(const short8*)(Vbf + c * 128 + kb);
    }
    #pragma unroll
    for (int mt = 0; mt < 4; mt++)
      #pragma unroll
      for (int nt = 0; nt < 4; nt++)
        acc[mt][nt] = __builtin_amdgcn_mfma_f32_16x16x32_bf16(af[mt], bfv[nt], acc[mt][nt], 0, 0, 0);
  }
  float ld = sld;
  #pragma unroll
  for (int mt = 0; mt < 4; mt++)
    #pragma unroll
    for (int nt = 0; nt < 4; nt++)
      #pragma unroll
      for (int r = 0; r < 4; r++) {
        int row = wr + mt * 16 + (lane >> 4) * 4 + r;
        int col = wc + nt * 16 + (lane & 15);
        float g = acc[mt][nt][r];
        out[(size_t)(bi * 128 + row) * MTEST + (bj * 128 + col)] =
          2.0f * g - qi[row] - qj[col] - ld;
      }
}

extern "C" void kernel_launch(void* const* d_in, const int* in_sizes, int n_in,
                              void* d_out, int out_size, void* d_ws, size_t ws_size,
                              hipStream_t stream) {
  (void)in_sizes; (void)n_in; (void)out_size; (void)ws_size;
  const float* X = (const float*)d_in[0];
  const float* test = (const float*)d_in[1];
  float* out = (float*)d_out;
  float* ws = (float*)d_ws;
  float* scal = ws + fSCAL;

  auto MAT = [&](int i) -> unsigned short* {
    return (unsigned short*)(ws + fMAT) + (size_t)i * 32768;
  };
  // slots: 0 SW, 1 SB, 2 Y1, 3 W/F, 4 Q/A1, 5 Y2, 6 Y3, 7 M1/Bq, 8 M, 9 C2,
  //        10 C4/b3, 11 XH, 12 T2, 13 T3, 14 T4, 15 Y5, 16-20 G0..G4,
  //        21 SWRAW(f32), 22 b2, 23 b1
  unsigned short *SW = MAT(0), *SB = MAT(1), *Y1 = MAT(2), *Wt = MAT(3), *Qt = MAT(4),
    *Y2 = MAT(5), *Y3 = MAT(6), *M1 = MAT(7), *Mm = MAT(8), *C2 = MAT(9), *C4 = MAT(10),
    *XH = MAT(11), *T2 = MAT(12), *T3 = MAT(13), *T4 = MAT(14), *Y5 = MAT(15),
    *G1 = MAT(17), *G2 = MAT(18), *G3 = MAT(19), *G4 = MAT(20),
    *G0 = MAT(16), *B3 = MAT(10), *B2 = MAT(22), *B1 = MAT(23),
    *Fm = MAT(3), *A1 = MAT(4), *Bq = MAT(7);

  k_class_mean<<<NCLS, 128, 0, stream>>>(X, ws);
  k_global_mean<<<1, 128, 0, stream>>>(ws);
  k_gt_partial<<<64, 256, 0, stream>>>(X, ws);
  k_reduce<<<64, 256, 0, stream>>>(ws);
  k_sb<<<4, 256, 0, stream>>>(ws);
  k_swfin<<<16, 256, 0, stream>>>(ws);
  // Newton-Schulz sqrt: Y1 = 1.5I-0.5S (done); two refinement iterations
  k_mm<<<4, 256, 0, stream>>>(Y1, Y1, Wt, nullptr, nullptr, 1.0f, nullptr, 0, 0, 0.0f, scal, -1);
  k_mm<<<4, 256, 0, stream>>>(SW, Wt, Qt, nullptr, nullptr, -1.0f, nullptr, 0, 0, 3.0f, scal, -1);
  k_mm<<<4, 256, 0, stream>>>(Y1, Qt, Y2, nullptr, nullptr, 0.5f, nullptr, 0, 0, 0.0f, scal, -1);
  k_mm<<<4, 256, 0, stream>>>(Y2, Y2, Wt, nullptr, nullptr, 1.0f, nullptr, 0, 0, 0.0f, scal, -1);
  k_mm<<<4, 256, 0, stream>>>(SW, Wt, Qt, nullptr, nullptr, -1.0f, nullptr, 0, 0, 3.0f, scal, -1);
  k_mm<<<4, 256, 0, stream>>>(Y2, Qt, Y3, nullptr, nullptr, 0.5f, nullptr, 0, 0, 0.0f, scal, -1);
  // M = Y*SB*Y (symmetric); C2 = M^2; C4 = M^4 (+ tr(M^8) partials -> scal[68..71])
  k_mm<<<4, 256, 0, stream>>>(Y3, SB, M1, nullptr, nullptr, 1.0f, nullptr, 0, 0, 0.0f, scal, -1);
  k_mm<<<4, 256, 0, stream>>>(M1, Y3, Mm, nullptr, nullptr, 1.0f, nullptr, 0, 0, 0.0f, scal, -1);
  k_mm<<<4, 256, 0, stream>>>(Mm, Mm, C2, nullptr, nullptr, 1.0f, nullptr, 0, 0, 0.0f, scal, -1);
  k_mm<<<4, 256, 0, stream>>>(C2, C2, C4, nullptr, nullptr, 1.0f, nullptr, 0, 0, 0.0f, scal, 68);
  k_coef<<<1, 64, 0, stream>>>(ws);
  k_xh_t2<<<16, 256, 0, stream>>>(ws);
  // Chebyshev basis in X: T3 = 2 XH T2 - XH; T4 = 2 T2^2 - I; Y5 = 2 T2 T3 - XH
  k_mm<<<4, 256, 0, stream>>>(XH, T2, T3, XH, nullptr, 2.0f, nullptr, -1.0f, 0, 0.0f, scal, -1);
  k_mm<<<4, 256, 0, stream>>>(T2, T2, T4, nullptr, nullptr, 2.0f, nullptr, 0, 0, -1.0f, scal, -1);
  k_mm<<<4, 256, 0, stream>>>(T2, T3, Y5, XH, nullptr, 2.0f, nullptr, -1.0f, 0, 0.0f, scal, -1);
  k_gform<<<16, 256, 0, stream>>>(ws);
  // Clenshaw in Y5 with matrix coefficients G0..G4 (b4 = G4)
  k_mm<<<4, 256, 0, stream>>>(Y5, G4, B3, G3, nullptr, 2.0f, nullptr, 1.0f, 0, 0.0f, scal, -1);
  k_mm<<<4, 256, 0, stream>>>(Y5, B3, B2, G4, G2, 2.0f, nullptr, -1.0f, 1.0f, 0.0f, scal, -1);
  k_mm<<<4, 256, 0, stream>>>(Y5, B2, B1, B3, G1, 2.0f, nullptr, -1.0f, 1.0f, 0.0f, scal, -1);
  k_mm<<<4, 256, 0, stream>>>(Y5, B1, Fm, B2, G0, 1.0f, nullptr, -1.0f, 1.0f, 0.0f, scal, 72);
  // B = (63/64)*inv_s * Y*F*Y
  k_mm<<<4, 256, 0, stream>>>(Y3, Fm, A1, nullptr, nullptr, 1.0f, nullptr, 0, 0, 0.0f, scal, -1);
  k_mm<<<4, 256, 0, stream>>>(A1, Y3, Bq, nullptr, nullptr, 1.0f, scal + 7, 0, 0, 0.0f, scal, -1);
  k_sym<<<16, 256, 0, stream>>>(ws);
  k_latent<<<64, 256, 0, stream>>>(test, ws);
  k_q<<<32, 256, 0, stream>>>(ws);
  k_pair<<<dim3(64, 64), 256, 0, stream>>>(ws, out);
}